// Round 13
// baseline (134.280 us; speedup 1.0000x reference)
//
#include <hip/hip_runtime.h>
#include <stdint.h>

typedef float          f32x4  __attribute__((ext_vector_type(4)));
typedef __bf16         bf16x8 __attribute__((ext_vector_type(8)));
typedef unsigned short u16x4  __attribute__((ext_vector_type(4)));
typedef unsigned short u16x8  __attribute__((ext_vector_type(8)));

__device__ __forceinline__ float bf2f(unsigned short u) {
    union { uint32_t i; float f; } v; v.i = ((uint32_t)u) << 16; return v.f;
}
__device__ __forceinline__ unsigned short bfc(float f) {
    return __builtin_bit_cast(unsigned short, (__bf16)f);
}
__device__ __forceinline__ f32x4 mfma16(bf16x8 a, bf16x8 b, f32x4 c) {
    return __builtin_amdgcn_mfma_f32_16x16x32_bf16(a, b, c, 0, 0, 0);
}
// async global->LDS, 16B per lane; LDS dest = wave-uniform base + lane*16
__device__ __forceinline__ void async16(const unsigned short* g, unsigned short* l) {
    __builtin_amdgcn_global_load_lds(
        (const __attribute__((address_space(1))) void*)g,
        (__attribute__((address_space(3))) void*)l, 16, 0, 0);
}

#define QSC 0.18033688f   /* 0.125 * log2(e): S produced in exp2 domain */

// ---------------------------------------------------------------------------
// Kernel 1: QKV GEMM.  C[o][n] = sum_c Wqkv[o][c] * X[b][c][n],  o in [0,768)
// f32 inputs -> bf16 LDS staging.  Q written pre-scaled by 0.125*log2e.
// Q,K layout [bh][n][d]; V layout [bh][d][m].
// XCD-chunked swizzle (768 = 8 x 96).
// ---------------------------------------------------------------------------
__global__ __launch_bounds__(256) void qkv_gemm(
    const float* __restrict__ x, const float* __restrict__ wqkv,
    unsigned short* __restrict__ Qb, unsigned short* __restrict__ Kb,
    unsigned short* __restrict__ Vb) {
    const int flat = (blockIdx.z * 32 + blockIdx.y) * 6 + blockIdx.x;  // 0..767
    const int v = (flat & 7) * 96 + (flat >> 3);    // bijective (768 = 8*96)
    const int mt = v % 6;
    const int rest = v / 6;
    const int nt = rest & 31;
    const int b  = rest >> 5;
    const int o0 = mt * 128, n0 = nt * 128;
    __shared__ __align__(16) unsigned short Wt[128 * 72];   // [o][c] pad 72
    __shared__ __align__(16) unsigned short Xt[128 * 72];   // [n][c] pad 72
    const int t = threadIdx.x;
    const int lane = t & 63, w = t >> 6;
    const int wr = w >> 1, wc = w & 1;
    const int l15 = lane & 15, g = lane >> 4;

    f32x4 acc[4][4];
    const f32x4 zero = {0.f, 0.f, 0.f, 0.f};
    for (int i = 0; i < 4; i++) for (int j = 0; j < 4; j++) acc[i][j] = zero;

    for (int k0 = 0; k0 < 256; k0 += 64) {
        {
            const int row = t >> 3, col = (t & 7) * 8;
            #pragma unroll
            for (int r = 0; r < 4; r++) {
                const float* p = wqkv + (size_t)(o0 + row + r * 32) * 256 + k0 + col;
                f32x4 v0 = *(const f32x4*)p;
                f32x4 v1 = *(const f32x4*)(p + 4);
                u16x8 o8 = { bfc(v0[0]), bfc(v0[1]), bfc(v0[2]), bfc(v0[3]),
                             bfc(v1[0]), bfc(v1[1]), bfc(v1[2]), bfc(v1[3]) };
                *(u16x8*)(&Wt[(row + r * 32) * 72 + col]) = o8;
            }
        }
        {
            const int cl = t >> 4, nl = (t & 15) * 8;
            #pragma unroll
            for (int r = 0; r < 4; r++) {
                const int c = k0 + cl + r * 16;
                const float* p = x + (size_t)(b * 512 + c) * 4096 + n0 + nl;
                f32x4 v0 = *(const f32x4*)p;
                f32x4 v1 = *(const f32x4*)(p + 4);
                #pragma unroll
                for (int j = 0; j < 4; j++) Xt[(nl + j) * 72 + cl + r * 16] = bfc(v0[j]);
                #pragma unroll
                for (int j = 0; j < 4; j++) Xt[(nl + 4 + j) * 72 + cl + r * 16] = bfc(v1[j]);
            }
        }
        __syncthreads();
        #pragma unroll
        for (int kk = 0; kk < 2; kk++) {
            bf16x8 af[4], bfr[4];
            #pragma unroll
            for (int i = 0; i < 4; i++)
                af[i] = *(const bf16x8*)(&Wt[(wr * 64 + i * 16 + l15) * 72 + kk * 32 + g * 8]);
            #pragma unroll
            for (int j = 0; j < 4; j++)
                bfr[j] = *(const bf16x8*)(&Xt[(wc * 64 + j * 16 + l15) * 72 + kk * 32 + g * 8]);
            #pragma unroll
            for (int i = 0; i < 4; i++)
                #pragma unroll
                for (int j = 0; j < 4; j++)
                    acc[i][j] = mfma16(af[i], bfr[j], acc[i][j]);
        }
        __syncthreads();
    }

    #pragma unroll
    for (int i = 0; i < 4; i++) {
        const int o = o0 + wr * 64 + i * 16 + g * 4;
        #pragma unroll
        for (int j = 0; j < 4; j++) {
            const int n = n0 + wc * 64 + j * 16 + l15;
            f32x4 a = acc[i][j];
            if (o < 256) {
                u16x4 pv = { bfc(a[0] * QSC), bfc(a[1] * QSC), bfc(a[2] * QSC), bfc(a[3] * QSC) };
                const int h = o >> 6, d = o & 63;
                *(u16x4*)(&Qb[(((size_t)(b * 4 + h)) * 4096 + n) * 64 + d]) = pv;
            } else if (o < 512) {
                u16x4 pv = { bfc(a[0]), bfc(a[1]), bfc(a[2]), bfc(a[3]) };
                const int oo = o - 256; const int h = oo >> 6, d = oo & 63;
                *(u16x4*)(&Kb[(((size_t)(b * 4 + h)) * 4096 + n) * 64 + d]) = pv;
            } else {
                const int oo = o - 512; const int h = oo >> 6, d = oo & 63;
                const size_t base = (((size_t)(b * 4 + h)) * 64 + d) * 4096 + n;
                Vb[base] = bfc(a[0]); Vb[base + 4096] = bfc(a[1]);
                Vb[base + 8192] = bfc(a[2]); Vb[base + 12288] = bfc(a[3]);
            }
        }
    }
}

// ---------------------------------------------------------------------------
// Kernel 2: flash attention, KV-split S=2, MAX-FREE softmax, fat waves
// (4 waves x 64 q-rows), KVBLK=64, 32 iters.  TRIPLE-buffered K/V LDS
// (48 KB) with counted s_waitcnt vmcnt(4) + raw s_barrier (T3/T4): the
// prefetch stays in flight across 2 iterations instead of being drained by
// __syncthreads' vmcnt(0) every iteration (r12 postmortem: that drain made
// iters cost 5600 cyc vs ~1500 of work).
// Invariants: at iter i entry a wave's outstanding = tiles i,i+1 (8 loads);
// vmcnt(4) retires tile i; barrier => ALL waves' tile-i DMAs landed;
// stage(i+2) into buf[(i-1)%3] is safe (tile i-1 fully consumed pre-barrier).
// P in registers via k-space relabel sigma; l via ones-MFMA.
// ---------------------------------------------------------------------------
__global__ __launch_bounds__(256, 2) void flash_attn(
    const unsigned short* __restrict__ Qb, const unsigned short* __restrict__ Kb,
    const unsigned short* __restrict__ Vb, unsigned short* __restrict__ Opart,
    float* __restrict__ ml) {
    __shared__ __align__(16) unsigned short Kt[3][64 * 64];   // 24 KB
    __shared__ __align__(16) unsigned short Vt[3][64 * 64];   // 24 KB

    // XCD-aware swizzle over 512 blocks (8 XCDs x 64)
    const int flat = (blockIdx.z * 16 + blockIdx.y) * 16 + blockIdx.x;
    const int nf = (flat & 7) * 64 + (flat >> 3);
    const int z  = nf >> 8;             // kv half: 0/1
    const int bh = (nf >> 4) & 15;      // 0..15
    const int nb = nf & 15;             // 0..15  (q-tile of 256)

    const int t = threadIdx.x, lane = t & 63, w = t >> 6;    // w = 0..3
    const int l15 = lane & 15, g = lane >> 4;
    const int xo = (l15 & 7) << 3;              // element-space XOR for K reads
    const int c0 = (g * 8) ^ xo, c1 = c0 ^ 32;
    // V b64 read column base (ushort units): block=(g>>1)^(l15&7), half=g&1
    const int vq = ((((g >> 1) ^ (l15 & 7)) << 3) | ((g & 1) << 2));

    // staging source addresses (pre-swizzled, within each 128B row)
    const int rb = lane >> 3;                                  // 0..7
    const int cbe = ((lane & 7) ^ rb) << 3;                    // element col offset
    const unsigned short* kgp = Kb + ((size_t)bh * 4096 + z * 2048 + w * 8 + rb) * 64 + cbe;
    const unsigned short* vgp = Vb + ((size_t)(bh * 64 + w * 8 + rb)) * 4096 + z * 2048 + cbe;

    auto stage = [&](int buf) {           // loads NEXT kv-tile, advances ptrs
        async16(kgp,          &Kt[buf][w * 512]);
        async16(kgp + 2048,   &Kt[buf][w * 512 + 2048]);
        async16(vgp,          &Vt[buf][w * 512]);
        async16(vgp + 131072, &Vt[buf][w * 512 + 2048]);
        kgp += 4096; vgp += 64;
    };

    // Q fragments (scaled into exp2 domain at QKV epilogue), 64 rows/wave
    bf16x8 qf[4][2];
    #pragma unroll
    for (int ntl = 0; ntl < 4; ++ntl) {
        const int nq = nb * 256 + w * 64 + ntl * 16 + l15;
        const unsigned short* qp = Qb + ((size_t)bh * 4096 + nq) * 64;
        qf[ntl][0] = *(const bf16x8*)(qp + g * 8);
        qf[ntl][1] = *(const bf16x8*)(qp + 32 + g * 8);
    }

    // ones A-fragment for the l-accumulating MFMA (bf16 1.0 = 0x3F80)
    const bf16x8 ones8 = __builtin_bit_cast(bf16x8,
        (u16x8){0x3F80, 0x3F80, 0x3F80, 0x3F80, 0x3F80, 0x3F80, 0x3F80, 0x3F80});

    f32x4 of[4][4];
    f32x4 lf[4];
    const f32x4 zero = {0.f, 0.f, 0.f, 0.f};
    #pragma unroll
    for (int dt = 0; dt < 4; ++dt)
        #pragma unroll
        for (int ntl = 0; ntl < 4; ++ntl) of[dt][ntl] = zero;
    lf[0] = zero; lf[1] = zero; lf[2] = zero; lf[3] = zero;

    stage(0);
    stage(1);

    int bufc = 0;                        // buffer holding the current tile
    for (int it = 0; it < 32; ++it) {
        // retire current tile's 4 loads (leave next tile's 4 in flight);
        // last iter has nothing behind it -> full drain
        if (it < 31) asm volatile("s_waitcnt vmcnt(4)" ::: "memory");
        else         asm volatile("s_waitcnt vmcnt(0)" ::: "memory");
        __builtin_amdgcn_s_barrier();    // all waves' current-tile DMAs landed
        if (it + 2 < 32) {
            const int nxt = (bufc + 2 >= 3) ? bufc - 1 : bufc + 2;
            stage(nxt);                  // overwrites tile it-1's buffer: safe
        }

        // read K and V fragments ONCE (reused by all 4 ntl)
        const unsigned short* Ktc = &Kt[bufc][0];
        const unsigned short* Vtc = &Vt[bufc][0];
        bf16x8 ka[4][2], va[4][2];
        #pragma unroll
        for (int mt = 0; mt < 4; ++mt) {
            const int kro = (mt * 16 + l15) * 64;
            ka[mt][0] = *(const bf16x8*)(&Ktc[kro + c0]);
            ka[mt][1] = *(const bf16x8*)(&Ktc[kro + c1]);
        }
        #pragma unroll
        for (int dt = 0; dt < 4; ++dt) {
            const unsigned short* vr = &Vtc[l15 * 64 + dt * 1024];
            u16x4 w00 = *(const u16x4*)(vr + (vq ^ 0));
            u16x4 w01 = *(const u16x4*)(vr + (vq ^ 16));
            u16x4 w10 = *(const u16x4*)(vr + (vq ^ 32));
            u16x4 w11 = *(const u16x4*)(vr + (vq ^ 48));
            va[dt][0] = __builtin_bit_cast(bf16x8,
                __builtin_shufflevector(w00, w01, 0, 1, 2, 3, 4, 5, 6, 7));
            va[dt][1] = __builtin_bit_cast(bf16x8,
                __builtin_shufflevector(w10, w11, 0, 1, 2, 3, 4, 5, 6, 7));
        }

        #pragma unroll
        for (int ntl = 0; ntl < 4; ++ntl) {
            // S^T (exp2 domain) for this 16-row slice
            f32x4 st[4];
            __builtin_amdgcn_s_setprio(1);
            #pragma unroll
            for (int mt = 0; mt < 4; ++mt)
                st[mt] = mfma16(ka[mt][1], qf[ntl][1],
                                mfma16(ka[mt][0], qf[ntl][0], zero));
            __builtin_amdgcn_s_setprio(0);

            // max-free softmax: P = exp2(S), packed into fragments
            u16x4 q0 = { bfc(__builtin_amdgcn_exp2f(st[0][0])),
                         bfc(__builtin_amdgcn_exp2f(st[0][1])),
                         bfc(__builtin_amdgcn_exp2f(st[0][2])),
                         bfc(__builtin_amdgcn_exp2f(st[0][3])) };
            u16x4 q1 = { bfc(__builtin_amdgcn_exp2f(st[1][0])),
                         bfc(__builtin_amdgcn_exp2f(st[1][1])),
                         bfc(__builtin_amdgcn_exp2f(st[1][2])),
                         bfc(__builtin_amdgcn_exp2f(st[1][3])) };
            u16x4 q2 = { bfc(__builtin_amdgcn_exp2f(st[2][0])),
                         bfc(__builtin_amdgcn_exp2f(st[2][1])),
                         bfc(__builtin_amdgcn_exp2f(st[2][2])),
                         bfc(__builtin_amdgcn_exp2f(st[2][3])) };
            u16x4 q3 = { bfc(__builtin_amdgcn_exp2f(st[3][0])),
                         bfc(__builtin_amdgcn_exp2f(st[3][1])),
                         bfc(__builtin_amdgcn_exp2f(st[3][2])),
                         bfc(__builtin_amdgcn_exp2f(st[3][3])) };
            bf16x8 pb0 = __builtin_bit_cast(bf16x8,
                __builtin_shufflevector(q0, q1, 0, 1, 2, 3, 4, 5, 6, 7));
            bf16x8 pb1 = __builtin_bit_cast(bf16x8,
                __builtin_shufflevector(q2, q3, 0, 1, 2, 3, 4, 5, 6, 7));

            // l + PV on the matrix pipe (operands all in registers)
            __builtin_amdgcn_s_setprio(1);
            lf[ntl] = mfma16(ones8, pb1, mfma16(ones8, pb0, lf[ntl]));
            #pragma unroll
            for (int dt = 0; dt < 4; ++dt)
                of[dt][ntl] = mfma16(va[dt][1], pb1,
                                     mfma16(va[dt][0], pb0, of[dt][ntl]));
            __builtin_amdgcn_s_setprio(0);
        }
        bufc = (bufc + 1 == 3) ? 0 : bufc + 1;
    }

    // epilogue: unnormalized O (bf16) + per-row l partials (lane-local)
    #pragma unroll
    for (int ntl = 0; ntl < 4; ++ntl) {
        const int nq = nb * 256 + w * 64 + ntl * 16 + l15;
        const size_t obase = ((size_t)((z * 16 + bh) * 4096 + nq)) * 64;
        #pragma unroll
        for (int dt = 0; dt < 4; ++dt) {
            u16x4 pv = { bfc(of[dt][ntl][0]), bfc(of[dt][ntl][1]),
                         bfc(of[dt][ntl][2]), bfc(of[dt][ntl][3]) };
            *(u16x4*)(&Opart[obase + dt * 16 + g * 4]) = pv;
        }
        if (g == 0) ml[z * 65536 + bh * 4096 + nq] = lf[ntl][0];
    }
}

// ---------------------------------------------------------------------------
// Kernel 3: proj GEMM with FUSED attention merge in the B staging:
// att = (O1+O2)/(l1+l2), BK=64 == head_dim.
// XCD-chunked swizzle (256 = 8 x 32).
// ---------------------------------------------------------------------------
__global__ __launch_bounds__(256) void proj_gemm(
    const unsigned short* __restrict__ Opart, const float* __restrict__ ml,
    const float* __restrict__ wproj,
    unsigned short* __restrict__ projbf, float* __restrict__ psum) {
    const int flat = (blockIdx.z * 32 + blockIdx.y) * 2 + blockIdx.x;  // 0..255
    const int v = (flat & 7) * 32 + (flat >> 3);    // bijective (256 = 8*32)
    const int mt = v & 1;
    const int rest = v >> 1;
    const int nt = rest & 31;
    const int b  = rest >> 5;
    const int o0 = mt * 128, n0 = nt * 128;
    __shared__ __align__(16) unsigned short Wt[128 * 72];
    __shared__ __align__(16) unsigned short Bt[128 * 72];
    const int t = threadIdx.x;
    const int lane = t & 63, w = t >> 6;
    const int wr = w >> 1, wc = w & 1;
    const int l15 = lane & 15, g = lane >> 4;

    f32x4 acc[4][4];
    const f32x4 zero = {0.f, 0.f, 0.f, 0.f};
    for (int i = 0; i < 4; i++) for (int j = 0; j < 4; j++) acc[i][j] = zero;

    for (int k0 = 0; k0 < 256; k0 += 64) {
        const int row = t >> 3, col = (t & 7) * 8;
        const int h = k0 >> 6;
        #pragma unroll
        for (int r = 0; r < 4; r++) {
            const float* p = wproj + (size_t)(o0 + row + r * 32) * 256 + k0 + col;
            f32x4 v0 = *(const f32x4*)p;
            f32x4 v1 = *(const f32x4*)(p + 4);
            u16x8 o8 = { bfc(v0[0]), bfc(v0[1]), bfc(v0[2]), bfc(v0[3]),
                         bfc(v1[0]), bfc(v1[1]), bfc(v1[2]), bfc(v1[3]) };
            *(u16x8*)(&Wt[(row + r * 32) * 72 + col]) = o8;
            // fused merge: att[b][n][h*64+col..] = (O1+O2)/(l1+l2)
            const int n = n0 + row + r * 32;
            const int qidx = (b * 4 + h) * 4096 + n;
            const float inv = 1.f / (ml[qidx] + ml[65536 + qidx]);
            u16x8 m1 = *(const u16x8*)(Opart + (size_t)qidx * 64 + col);
            u16x8 m2 = *(const u16x8*)(Opart + 4194304u + (size_t)qidx * 64 + col);
            u16x8 a;
            #pragma unroll
            for (int j = 0; j < 8; ++j) a[j] = bfc((bf2f(m1[j]) + bf2f(m2[j])) * inv);
            *(u16x8*)(&Bt[(row + r * 32) * 72 + col]) = a;
        }
        __syncthreads();
        #pragma unroll
        for (int kk = 0; kk < 2; kk++) {
            bf16x8 af[4], bfr[4];
            #pragma unroll
            for (int i = 0; i < 4; i++)
                af[i] = *(const bf16x8*)(&Wt[(wr * 64 + i * 16 + l15) * 72 + kk * 32 + g * 8]);
            #pragma unroll
            for (int j = 0; j < 4; j++)
                bfr[j] = *(const bf16x8*)(&Bt[(wc * 64 + j * 16 + l15) * 72 + kk * 32 + g * 8]);
            #pragma unroll
            for (int i = 0; i < 4; i++)
                #pragma unroll
                for (int j = 0; j < 4; j++)
                    acc[i][j] = mfma16(af[i], bfr[j], acc[i][j]);
        }
        __syncthreads();
    }

    #pragma unroll
    for (int i = 0; i < 4; i++) {
        const int o = o0 + wr * 64 + i * 16 + g * 4;
        #pragma unroll
        for (int j = 0; j < 4; j++) {
            const int n = n0 + wc * 64 + j * 16 + l15;
            f32x4 a = acc[i][j];
            #pragma unroll
            for (int r = 0; r < 4; r++)
                projbf[((size_t)(b * 256 + o + r)) * 4096 + n] = bfc(a[r]);
        }
        // BN partials over this wave's 64 n-columns (f32, pre-rounding)
        f32x4 s = acc[i][0], q;
        #pragma unroll
        for (int r = 0; r < 4; ++r) q[r] = acc[i][0][r] * acc[i][0][r];
        #pragma unroll
        for (int j = 1; j < 4; ++j)
            #pragma unroll
            for (int r = 0; r < 4; ++r) {
                s[r] += acc[i][j][r];
                q[r] = fmaf(acc[i][j][r], acc[i][j][r], q[r]);
            }
        #pragma unroll
        for (int m = 1; m < 16; m <<= 1) {
            #pragma unroll
            for (int r = 0; r < 4; ++r) {
                s[r] += __shfl_xor(s[r], m, 64);
                q[r] += __shfl_xor(q[r], m, 64);
            }
        }
        if (l15 == 0) {
            const int slot = (b * 32 + nt) * 2 + wc;
            *(f32x4*)(&psum[slot * 256 + o]) = s;
            *(f32x4*)(&psum[65536 + slot * 256 + o]) = q;
        }
    }
}

// ---------------------------------------------------------------------------
// Kernel 4: BN finalize.  One block per channel o; 256 threads over slots.
// ---------------------------------------------------------------------------
__global__ __launch_bounds__(256) void bn_finalize(const float* __restrict__ psum,
                                                   float* __restrict__ stats) {
    const int o = blockIdx.x, t = threadIdx.x;
    const int lane = t & 63, w = t >> 6;
    float s = psum[t * 256 + o];
    float q = psum[65536 + t * 256 + o];
    #pragma unroll
    for (int m = 1; m < 64; m <<= 1) {
        s += __shfl_xor(s, m, 64);
        q += __shfl_xor(q, m, 64);
    }
    __shared__ float red[8];
    if (lane == 0) { red[w] = s; red[4 + w] = q; }
    __syncthreads();
    if (t == 0) {
        const float S = red[0] + red[1] + red[2] + red[3];
        const float Q = red[4] + red[5] + red[6] + red[7];
        const float mean = S * (1.f / 16384.f);
        const float var = Q * (1.f / 16384.f) - mean * mean;
        stats[o] = mean;
        stats[256 + o] = rsqrtf(var + 1e-5f);
    }
}

// ---------------------------------------------------------------------------
// Kernel 5: BN apply + gamma/beta + concat skip.  proj bf16 in, f32 out.
// ---------------------------------------------------------------------------
__global__ __launch_bounds__(256) void bn_apply(
    const unsigned short* __restrict__ projbf, const float* __restrict__ stats,
    const float* __restrict__ gamma, const float* __restrict__ beta,
    const float* __restrict__ x, float* __restrict__ out) {
    const size_t idx8 = ((size_t)blockIdx.x * 256 + threadIdx.x) * 8;
    const int n  = (int)(idx8 & 4095);
    const int ch = (int)((idx8 >> 12) & 511);
    const int b  = (int)(idx8 >> 21);
    if (ch < 256) {
        const float mean = stats[ch], rstd = stats[256 + ch];
        const float sc = gamma[ch] * rstd;
        const float sh = beta[ch] - mean * sc;
        u16x8 pv = *(const u16x8*)(projbf + (((size_t)(b * 256 + ch)) << 12) + n);
        f32x4 o0, o1;
        #pragma unroll
        for (int j = 0; j < 4; j++) { o0[j] = bf2f(pv[j]) * sc + sh; o1[j] = bf2f(pv[4 + j]) * sc + sh; }
        *(f32x4*)(out + idx8) = o0;
        *(f32x4*)(out + idx8 + 4) = o1;
    } else {
        *(f32x4*)(out + idx8)     = *(const f32x4*)(x + idx8);
        *(f32x4*)(out + idx8 + 4) = *(const f32x4*)(x + idx8 + 4);
    }
}

// ---------------------------------------------------------------------------
// Workspace overlay (offsets in bytes):
//   phase A (qkv+flash):  Qb 0..8M, Kb 8..16M, Vb 16..24M,
//                         Opart 24..40M (both halves), ml 41..41.5M (f32)
//   phase B (proj+bn):    projbf 0..8M (over dead Qb),
//                         psum 9..9.5M (over dead Kb), stats 9.75M
// ---------------------------------------------------------------------------
extern "C" void kernel_launch(void* const* d_in, const int* in_sizes, int n_in,
                              void* d_out, int out_size, void* d_ws, size_t ws_size,
                              hipStream_t stream) {
    const float* x     = (const float*)d_in[0];
    const float* wqkv  = (const float*)d_in[1];
    const float* wproj = (const float*)d_in[2];
    const float* gamma = (const float*)d_in[3];
    const float* beta  = (const float*)d_in[4];
    float* out = (float*)d_out;

    char* ws = (char*)d_ws;
    unsigned short* Qb     = (unsigned short*)(ws);
    unsigned short* Kb     = (unsigned short*)(ws + (8ull  << 20));
    unsigned short* Vb     = (unsigned short*)(ws + (16ull << 20));
    unsigned short* Opart  = (unsigned short*)(ws + (24ull << 20));
    float*          ml     = (float*)(ws + (41ull << 20));
    unsigned short* projbf = (unsigned short*)(ws);                  // over Qb
    float*          psum   = (float*)(ws + (9ull << 20));            // over Kb
    float*          stats  = (float*)(ws + (9ull << 20) + (768u << 10));

    qkv_gemm   <<<dim3(6, 32, 4),  256, 0, stream>>>(x, wqkv, Qb, Kb, Vb);
    flash_attn <<<dim3(16, 16, 2), 256, 0, stream>>>(Qb, Kb, Vb, Opart, ml);
    proj_gemm  <<<dim3(2, 32, 4),  256, 0, stream>>>(Opart, ml, wproj, projbf, psum);
    bn_finalize<<<256,             256, 0, stream>>>(psum, stats);
    bn_apply   <<<4096,            256, 0, stream>>>(projbf, stats, gamma, beta, x, out);
}

// Round 15
// 132.902 us; speedup vs baseline: 1.0104x; 1.0104x over previous
//
#include <hip/hip_runtime.h>
#include <stdint.h>

typedef float          f32x4  __attribute__((ext_vector_type(4)));
typedef __bf16         bf16x8 __attribute__((ext_vector_type(8)));
typedef unsigned short u16x4  __attribute__((ext_vector_type(4)));
typedef unsigned short u16x8  __attribute__((ext_vector_type(8)));

__device__ __forceinline__ float bf2f(unsigned short u) {
    union { uint32_t i; float f; } v; v.i = ((uint32_t)u) << 16; return v.f;
}
__device__ __forceinline__ unsigned short bfc(float f) {
    return __builtin_bit_cast(unsigned short, (__bf16)f);
}
__device__ __forceinline__ f32x4 mfma16(bf16x8 a, bf16x8 b, f32x4 c) {
    return __builtin_amdgcn_mfma_f32_16x16x32_bf16(a, b, c, 0, 0, 0);
}
// async global->LDS, 16B per lane; LDS dest = wave-uniform base + lane*16
__device__ __forceinline__ void async16(const unsigned short* g, unsigned short* l) {
    __builtin_amdgcn_global_load_lds(
        (const __attribute__((address_space(1))) void*)g,
        (__attribute__((address_space(3))) void*)l, 16, 0, 0);
}

#define QSC 0.18033688f   /* 0.125 * log2(e): S produced in exp2 domain */

// ---------------------------------------------------------------------------
// Kernel 1: QKV GEMM.  C[o][n] = sum_c Wqkv[o][c] * X[b][c][n],  o in [0,768)
// f32 inputs -> bf16 LDS staging.  Q written pre-scaled by 0.125*log2e.
// Q,K layout [bh][n][d]; V layout [bh][d][m].
// XCD-chunked swizzle (768 = 8 x 96).
// ---------------------------------------------------------------------------
__global__ __launch_bounds__(256) void qkv_gemm(
    const float* __restrict__ x, const float* __restrict__ wqkv,
    unsigned short* __restrict__ Qb, unsigned short* __restrict__ Kb,
    unsigned short* __restrict__ Vb) {
    const int flat = (blockIdx.z * 32 + blockIdx.y) * 6 + blockIdx.x;  // 0..767
    const int v = (flat & 7) * 96 + (flat >> 3);    // bijective (768 = 8*96)
    const int mt = v % 6;
    const int rest = v / 6;
    const int nt = rest & 31;
    const int b  = rest >> 5;
    const int o0 = mt * 128, n0 = nt * 128;
    __shared__ __align__(16) unsigned short Wt[128 * 72];   // [o][c] pad 72
    __shared__ __align__(16) unsigned short Xt[128 * 72];   // [n][c] pad 72
    const int t = threadIdx.x;
    const int lane = t & 63, w = t >> 6;
    const int wr = w >> 1, wc = w & 1;
    const int l15 = lane & 15, g = lane >> 4;

    f32x4 acc[4][4];
    const f32x4 zero = {0.f, 0.f, 0.f, 0.f};
    for (int i = 0; i < 4; i++) for (int j = 0; j < 4; j++) acc[i][j] = zero;

    for (int k0 = 0; k0 < 256; k0 += 64) {
        {
            const int row = t >> 3, col = (t & 7) * 8;
            #pragma unroll
            for (int r = 0; r < 4; r++) {
                const float* p = wqkv + (size_t)(o0 + row + r * 32) * 256 + k0 + col;
                f32x4 v0 = *(const f32x4*)p;
                f32x4 v1 = *(const f32x4*)(p + 4);
                u16x8 o8 = { bfc(v0[0]), bfc(v0[1]), bfc(v0[2]), bfc(v0[3]),
                             bfc(v1[0]), bfc(v1[1]), bfc(v1[2]), bfc(v1[3]) };
                *(u16x8*)(&Wt[(row + r * 32) * 72 + col]) = o8;
            }
        }
        {
            const int cl = t >> 4, nl = (t & 15) * 8;
            #pragma unroll
            for (int r = 0; r < 4; r++) {
                const int c = k0 + cl + r * 16;
                const float* p = x + (size_t)(b * 512 + c) * 4096 + n0 + nl;
                f32x4 v0 = *(const f32x4*)p;
                f32x4 v1 = *(const f32x4*)(p + 4);
                #pragma unroll
                for (int j = 0; j < 4; j++) Xt[(nl + j) * 72 + cl + r * 16] = bfc(v0[j]);
                #pragma unroll
                for (int j = 0; j < 4; j++) Xt[(nl + 4 + j) * 72 + cl + r * 16] = bfc(v1[j]);
            }
        }
        __syncthreads();
        #pragma unroll
        for (int kk = 0; kk < 2; kk++) {
            bf16x8 af[4], bfr[4];
            #pragma unroll
            for (int i = 0; i < 4; i++)
                af[i] = *(const bf16x8*)(&Wt[(wr * 64 + i * 16 + l15) * 72 + kk * 32 + g * 8]);
            #pragma unroll
            for (int j = 0; j < 4; j++)
                bfr[j] = *(const bf16x8*)(&Xt[(wc * 64 + j * 16 + l15) * 72 + kk * 32 + g * 8]);
            #pragma unroll
            for (int i = 0; i < 4; i++)
                #pragma unroll
                for (int j = 0; j < 4; j++)
                    acc[i][j] = mfma16(af[i], bfr[j], acc[i][j]);
        }
        __syncthreads();
    }

    #pragma unroll
    for (int i = 0; i < 4; i++) {
        const int o = o0 + wr * 64 + i * 16 + g * 4;
        #pragma unroll
        for (int j = 0; j < 4; j++) {
            const int n = n0 + wc * 64 + j * 16 + l15;
            f32x4 a = acc[i][j];
            if (o < 256) {
                u16x4 pv = { bfc(a[0] * QSC), bfc(a[1] * QSC), bfc(a[2] * QSC), bfc(a[3] * QSC) };
                const int h = o >> 6, d = o & 63;
                *(u16x4*)(&Qb[(((size_t)(b * 4 + h)) * 4096 + n) * 64 + d]) = pv;
            } else if (o < 512) {
                u16x4 pv = { bfc(a[0]), bfc(a[1]), bfc(a[2]), bfc(a[3]) };
                const int oo = o - 256; const int h = oo >> 6, d = oo & 63;
                *(u16x4*)(&Kb[(((size_t)(b * 4 + h)) * 4096 + n) * 64 + d]) = pv;
            } else {
                const int oo = o - 512; const int h = oo >> 6, d = oo & 63;
                const size_t base = (((size_t)(b * 4 + h)) * 64 + d) * 4096 + n;
                Vb[base] = bfc(a[0]); Vb[base + 4096] = bfc(a[1]);
                Vb[base + 8192] = bfc(a[2]); Vb[base + 12288] = bfc(a[3]);
            }
        }
    }
}

// ---------------------------------------------------------------------------
// Kernel 2: flash attention, KV-split S=2 (2048-wide halves), MAX-FREE
// softmax, fat waves: 4 waves x 64 q-rows (QBLK=256), KVBLK=64, 32 iters.
// K and V fragments read from LDS ONCE per iteration, reused by 4 ntl
// sub-blocks.  K,V double-buffered [64][64] LDS (32 KB) via global_load_lds
// + XOR swizzle.  P in registers via k-space relabel sigma; l via ones-MFMA.
// Writes UNNORMALIZED O (bf16) + per-row l partials.
// ---------------------------------------------------------------------------
__global__ __launch_bounds__(256, 2) void flash_attn(
    const unsigned short* __restrict__ Qb, const unsigned short* __restrict__ Kb,
    const unsigned short* __restrict__ Vb, unsigned short* __restrict__ Opart,
    float* __restrict__ ml) {
    __shared__ __align__(16) unsigned short Kt[2][64 * 64];   // 16 KB
    __shared__ __align__(16) unsigned short Vt[2][64 * 64];   // 16 KB

    // XCD-aware swizzle over 512 blocks (8 XCDs x 64)
    const int flat = (blockIdx.z * 16 + blockIdx.y) * 16 + blockIdx.x;
    const int nf = (flat & 7) * 64 + (flat >> 3);
    const int z  = nf >> 8;             // kv half: 0/1
    const int bh = (nf >> 4) & 15;      // 0..15
    const int nb = nf & 15;             // 0..15  (q-tile of 256)

    const int t = threadIdx.x, lane = t & 63, w = t >> 6;    // w = 0..3
    const int l15 = lane & 15, g = lane >> 4;
    const int xo = (l15 & 7) << 3;              // element-space XOR for K reads
    const int c0 = (g * 8) ^ xo, c1 = c0 ^ 32;
    // V b64 read column base (ushort units): block=(g>>1)^(l15&7), half=g&1
    const int vq = ((((g >> 1) ^ (l15 & 7)) << 3) | ((g & 1) << 2));

    // staging source addresses (pre-swizzled, within each 128B row)
    const int rb = lane >> 3;                                  // 0..7
    const int cbe = ((lane & 7) ^ rb) << 3;                    // element col offset
    const unsigned short* kgp = Kb + ((size_t)bh * 4096 + z * 2048 + w * 8 + rb) * 64 + cbe;
    const unsigned short* vgp = Vb + ((size_t)(bh * 64 + w * 8 + rb)) * 4096 + z * 2048 + cbe;

    auto stage = [&](int buf) {           // loads NEXT kv-tile, advances ptrs
        async16(kgp,          &Kt[buf][w * 512]);
        async16(kgp + 2048,   &Kt[buf][w * 512 + 2048]);
        async16(vgp,          &Vt[buf][w * 512]);
        async16(vgp + 131072, &Vt[buf][w * 512 + 2048]);
        kgp += 4096; vgp += 64;
    };

    // Q fragments (scaled into exp2 domain at QKV epilogue), 64 rows/wave
    bf16x8 qf[4][2];
    #pragma unroll
    for (int ntl = 0; ntl < 4; ++ntl) {
        const int nq = nb * 256 + w * 64 + ntl * 16 + l15;
        const unsigned short* qp = Qb + ((size_t)bh * 4096 + nq) * 64;
        qf[ntl][0] = *(const bf16x8*)(qp + g * 8);
        qf[ntl][1] = *(const bf16x8*)(qp + 32 + g * 8);
    }

    // ones A-fragment for the l-accumulating MFMA (bf16 1.0 = 0x3F80)
    const bf16x8 ones8 = __builtin_bit_cast(bf16x8,
        (u16x8){0x3F80, 0x3F80, 0x3F80, 0x3F80, 0x3F80, 0x3F80, 0x3F80, 0x3F80});

    f32x4 of[4][4];
    f32x4 lf[4];
    const f32x4 zero = {0.f, 0.f, 0.f, 0.f};
    #pragma unroll
    for (int dt = 0; dt < 4; ++dt)
        #pragma unroll
        for (int ntl = 0; ntl < 4; ++ntl) of[dt][ntl] = zero;
    lf[0] = zero; lf[1] = zero; lf[2] = zero; lf[3] = zero;

    stage(0);
    __syncthreads();

    for (int itp = 0; itp < 16; ++itp) {
        #pragma unroll
        for (int cur = 0; cur < 2; ++cur) {          // cur is compile-time
            if (itp * 2 + cur < 31) stage(cur ^ 1);

            // read K and V fragments ONCE (reused by all 4 ntl)
            bf16x8 ka[4][2], va[4][2];
            #pragma unroll
            for (int mt = 0; mt < 4; ++mt) {
                const int kro = (mt * 16 + l15) * 64;
                ka[mt][0] = *(const bf16x8*)(&Kt[cur][kro + c0]);
                ka[mt][1] = *(const bf16x8*)(&Kt[cur][kro + c1]);
            }
            #pragma unroll
            for (int dt = 0; dt < 4; ++dt) {
                const unsigned short* vr = &Vt[cur][l15 * 64 + dt * 1024];
                u16x4 w00 = *(const u16x4*)(vr + (vq ^ 0));
                u16x4 w01 = *(const u16x4*)(vr + (vq ^ 16));
                u16x4 w10 = *(const u16x4*)(vr + (vq ^ 32));
                u16x4 w11 = *(const u16x4*)(vr + (vq ^ 48));
                va[dt][0] = __builtin_bit_cast(bf16x8,
                    __builtin_shufflevector(w00, w01, 0, 1, 2, 3, 4, 5, 6, 7));
                va[dt][1] = __builtin_bit_cast(bf16x8,
                    __builtin_shufflevector(w10, w11, 0, 1, 2, 3, 4, 5, 6, 7));
            }

            #pragma unroll
            for (int ntl = 0; ntl < 4; ++ntl) {
                // S^T (exp2 domain) for this 16-row slice
                f32x4 st[4];
                __builtin_amdgcn_s_setprio(1);
                #pragma unroll
                for (int mt = 0; mt < 4; ++mt)
                    st[mt] = mfma16(ka[mt][1], qf[ntl][1],
                                    mfma16(ka[mt][0], qf[ntl][0], zero));
                __builtin_amdgcn_s_setprio(0);

                // max-free softmax: P = exp2(S), packed into fragments
                u16x4 q0 = { bfc(__builtin_amdgcn_exp2f(st[0][0])),
                             bfc(__builtin_amdgcn_exp2f(st[0][1])),
                             bfc(__builtin_amdgcn_exp2f(st[0][2])),
                             bfc(__builtin_amdgcn_exp2f(st[0][3])) };
                u16x4 q1 = { bfc(__builtin_amdgcn_exp2f(st[1][0])),
                             bfc(__builtin_amdgcn_exp2f(st[1][1])),
                             bfc(__builtin_amdgcn_exp2f(st[1][2])),
                             bfc(__builtin_amdgcn_exp2f(st[1][3])) };
                u16x4 q2 = { bfc(__builtin_amdgcn_exp2f(st[2][0])),
                             bfc(__builtin_amdgcn_exp2f(st[2][1])),
                             bfc(__builtin_amdgcn_exp2f(st[2][2])),
                             bfc(__builtin_amdgcn_exp2f(st[2][3])) };
                u16x4 q3 = { bfc(__builtin_amdgcn_exp2f(st[3][0])),
                             bfc(__builtin_amdgcn_exp2f(st[3][1])),
                             bfc(__builtin_amdgcn_exp2f(st[3][2])),
                             bfc(__builtin_amdgcn_exp2f(st[3][3])) };
                bf16x8 pb0 = __builtin_bit_cast(bf16x8,
                    __builtin_shufflevector(q0, q1, 0, 1, 2, 3, 4, 5, 6, 7));
                bf16x8 pb1 = __builtin_bit_cast(bf16x8,
                    __builtin_shufflevector(q2, q3, 0, 1, 2, 3, 4, 5, 6, 7));

                // l + PV on the matrix pipe (operands all in registers)
                __builtin_amdgcn_s_setprio(1);
                lf[ntl] = mfma16(ones8, pb1, mfma16(ones8, pb0, lf[ntl]));
                #pragma unroll
                for (int dt = 0; dt < 4; ++dt)
                    of[dt][ntl] = mfma16(va[dt][1], pb1,
                                         mfma16(va[dt][0], pb0, of[dt][ntl]));
                __builtin_amdgcn_s_setprio(0);
            }
            __syncthreads();        // drains prefetch + guards buffer swap
        }
    }

    // epilogue: unnormalized O (bf16) + per-row l partials (lane-local)
    #pragma unroll
    for (int ntl = 0; ntl < 4; ++ntl) {
        const int nq = nb * 256 + w * 64 + ntl * 16 + l15;
        const size_t obase = ((size_t)((z * 16 + bh) * 4096 + nq)) * 64;
        #pragma unroll
        for (int dt = 0; dt < 4; ++dt) {
            u16x4 pv = { bfc(of[dt][ntl][0]), bfc(of[dt][ntl][1]),
                         bfc(of[dt][ntl][2]), bfc(of[dt][ntl][3]) };
            *(u16x4*)(&Opart[obase + dt * 16 + g * 4]) = pv;
        }
        if (g == 0) ml[z * 65536 + bh * 4096 + nq] = lf[ntl][0];
    }
}

// ---------------------------------------------------------------------------
// Kernel 3: proj GEMM with FUSED attention merge in the B staging:
// att = (O1+O2)/(l1+l2), BK=64 == head_dim.
// XCD-chunked swizzle (256 = 8 x 32).
// ---------------------------------------------------------------------------
__global__ __launch_bounds__(256) void proj_gemm(
    const unsigned short* __restrict__ Opart, const float* __restrict__ ml,
    const float* __restrict__ wproj,
    unsigned short* __restrict__ projbf, float* __restrict__ psum) {
    const int flat = (blockIdx.z * 32 + blockIdx.y) * 2 + blockIdx.x;  // 0..255
    const int v = (flat & 7) * 32 + (flat >> 3);    // bijective (256 = 8*32)
    const int mt = v & 1;
    const int rest = v >> 1;
    const int nt = rest & 31;
    const int b  = rest >> 5;
    const int o0 = mt * 128, n0 = nt * 128;
    __shared__ __align__(16) unsigned short Wt[128 * 72];
    __shared__ __align__(16) unsigned short Bt[128 * 72];
    const int t = threadIdx.x;
    const int lane = t & 63, w = t >> 6;
    const int wr = w >> 1, wc = w & 1;
    const int l15 = lane & 15, g = lane >> 4;

    f32x4 acc[4][4];
    const f32x4 zero = {0.f, 0.f, 0.f, 0.f};
    for (int i = 0; i < 4; i++) for (int j = 0; j < 4; j++) acc[i][j] = zero;

    for (int k0 = 0; k0 < 256; k0 += 64) {
        const int row = t >> 3, col = (t & 7) * 8;
        const int h = k0 >> 6;
        #pragma unroll
        for (int r = 0; r < 4; r++) {
            const float* p = wproj + (size_t)(o0 + row + r * 32) * 256 + k0 + col;
            f32x4 v0 = *(const f32x4*)p;
            f32x4 v1 = *(const f32x4*)(p + 4);
            u16x8 o8 = { bfc(v0[0]), bfc(v0[1]), bfc(v0[2]), bfc(v0[3]),
                         bfc(v1[0]), bfc(v1[1]), bfc(v1[2]), bfc(v1[3]) };
            *(u16x8*)(&Wt[(row + r * 32) * 72 + col]) = o8;
            // fused merge: att[b][n][h*64+col..] = (O1+O2)/(l1+l2)
            const int n = n0 + row + r * 32;
            const int qidx = (b * 4 + h) * 4096 + n;
            const float inv = 1.f / (ml[qidx] + ml[65536 + qidx]);
            u16x8 m1 = *(const u16x8*)(Opart + (size_t)qidx * 64 + col);
            u16x8 m2 = *(const u16x8*)(Opart + 4194304u + (size_t)qidx * 64 + col);
            u16x8 a;
            #pragma unroll
            for (int j = 0; j < 8; ++j) a[j] = bfc((bf2f(m1[j]) + bf2f(m2[j])) * inv);
            *(u16x8*)(&Bt[(row + r * 32) * 72 + col]) = a;
        }
        __syncthreads();
        #pragma unroll
        for (int kk = 0; kk < 2; kk++) {
            bf16x8 af[4], bfr[4];
            #pragma unroll
            for (int i = 0; i < 4; i++)
                af[i] = *(const bf16x8*)(&Wt[(wr * 64 + i * 16 + l15) * 72 + kk * 32 + g * 8]);
            #pragma unroll
            for (int j = 0; j < 4; j++)
                bfr[j] = *(const bf16x8*)(&Bt[(wc * 64 + j * 16 + l15) * 72 + kk * 32 + g * 8]);
            #pragma unroll
            for (int i = 0; i < 4; i++)
                #pragma unroll
                for (int j = 0; j < 4; j++)
                    acc[i][j] = mfma16(af[i], bfr[j], acc[i][j]);
        }
        __syncthreads();
    }

    #pragma unroll
    for (int i = 0; i < 4; i++) {
        const int o = o0 + wr * 64 + i * 16 + g * 4;
        #pragma unroll
        for (int j = 0; j < 4; j++) {
            const int n = n0 + wc * 64 + j * 16 + l15;
            f32x4 a = acc[i][j];
            #pragma unroll
            for (int r = 0; r < 4; r++)
                projbf[((size_t)(b * 256 + o + r)) * 4096 + n] = bfc(a[r]);
        }
        // BN partials over this wave's 64 n-columns (f32, pre-rounding)
        f32x4 s = acc[i][0], q;
        #pragma unroll
        for (int r = 0; r < 4; ++r) q[r] = acc[i][0][r] * acc[i][0][r];
        #pragma unroll
        for (int j = 1; j < 4; ++j)
            #pragma unroll
            for (int r = 0; r < 4; ++r) {
                s[r] += acc[i][j][r];
                q[r] = fmaf(acc[i][j][r], acc[i][j][r], q[r]);
            }
        #pragma unroll
        for (int m = 1; m < 16; m <<= 1) {
            #pragma unroll
            for (int r = 0; r < 4; ++r) {
                s[r] += __shfl_xor(s[r], m, 64);
                q[r] += __shfl_xor(q[r], m, 64);
            }
        }
        if (l15 == 0) {
            const int slot = (b * 32 + nt) * 2 + wc;
            *(f32x4*)(&psum[slot * 256 + o]) = s;
            *(f32x4*)(&psum[65536 + slot * 256 + o]) = q;
        }
    }
}

// ---------------------------------------------------------------------------
// Kernel 4: BN finalize.  One block per channel o; 256 threads over slots.
// ---------------------------------------------------------------------------
__global__ __launch_bounds__(256) void bn_finalize(const float* __restrict__ psum,
                                                   float* __restrict__ stats) {
    const int o = blockIdx.x, t = threadIdx.x;
    const int lane = t & 63, w = t >> 6;
    float s = psum[t * 256 + o];
    float q = psum[65536 + t * 256 + o];
    #pragma unroll
    for (int m = 1; m < 64; m <<= 1) {
        s += __shfl_xor(s, m, 64);
        q += __shfl_xor(q, m, 64);
    }
    __shared__ float red[8];
    if (lane == 0) { red[w] = s; red[4 + w] = q; }
    __syncthreads();
    if (t == 0) {
        const float S = red[0] + red[1] + red[2] + red[3];
        const float Q = red[4] + red[5] + red[6] + red[7];
        const float mean = S * (1.f / 16384.f);
        const float var = Q * (1.f / 16384.f) - mean * mean;
        stats[o] = mean;
        stats[256 + o] = rsqrtf(var + 1e-5f);
    }
}

// ---------------------------------------------------------------------------
// Kernel 5: BN apply + gamma/beta + concat skip.  proj bf16 in, f32 out.
// ---------------------------------------------------------------------------
__global__ __launch_bounds__(256) void bn_apply(
    const unsigned short* __restrict__ projbf, const float* __restrict__ stats,
    const float* __restrict__ gamma, const float* __restrict__ beta,
    const float* __restrict__ x, float* __restrict__ out) {
    const size_t idx8 = ((size_t)blockIdx.x * 256 + threadIdx.x) * 8;
    const int n  = (int)(idx8 & 4095);
    const int ch = (int)((idx8 >> 12) & 511);
    const int b  = (int)(idx8 >> 21);
    if (ch < 256) {
        const float mean = stats[ch], rstd = stats[256 + ch];
        const float sc = gamma[ch] * rstd;
        const float sh = beta[ch] - mean * sc;
        u16x8 pv = *(const u16x8*)(projbf + (((size_t)(b * 256 + ch)) << 12) + n);
        f32x4 o0, o1;
        #pragma unroll
        for (int j = 0; j < 4; j++) { o0[j] = bf2f(pv[j]) * sc + sh; o1[j] = bf2f(pv[4 + j]) * sc + sh; }
        *(f32x4*)(out + idx8) = o0;
        *(f32x4*)(out + idx8 + 4) = o1;
    } else {
        *(f32x4*)(out + idx8)     = *(const f32x4*)(x + idx8);
        *(f32x4*)(out + idx8 + 4) = *(const f32x4*)(x + idx8 + 4);
    }
}

// ---------------------------------------------------------------------------
// Workspace overlay (offsets in bytes):
//   phase A (qkv+flash):  Qb 0..8M, Kb 8..16M, Vb 16..24M,
//                         Opart 24..40M (both halves), ml 41..41.5M (f32)
//   phase B (proj+bn):    projbf 0..8M (over dead Qb),
//                         psum 9..9.5M (over dead Kb), stats 9.75M
// ---------------------------------------------------------------------------
extern "C" void kernel_launch(void* const* d_in, const int* in_sizes, int n_in,
                              void* d_out, int out_size, void* d_ws, size_t ws_size,
                              hipStream_t stream) {
    const float* x     = (const float*)d_in[0];
    const float* wqkv  = (const float*)d_in[1];
    const float* wproj = (const float*)d_in[2];
    const float* gamma = (const float*)d_in[3];
    const float* beta  = (const float*)d_in[4];
    float* out = (float*)d_out;

    char* ws = (char*)d_ws;
    unsigned short* Qb     = (unsigned short*)(ws);
    unsigned short* Kb     = (unsigned short*)(ws + (8ull  << 20));
    unsigned short* Vb     = (unsigned short*)(ws + (16ull << 20));
    unsigned short* Opart  = (unsigned short*)(ws + (24ull << 20));
    float*          ml     = (float*)(ws + (41ull << 20));
    unsigned short* projbf = (unsigned short*)(ws);                  // over Qb
    float*          psum   = (float*)(ws + (9ull << 20));            // over Kb
    float*          stats  = (float*)(ws + (9ull << 20) + (768u << 10));

    qkv_gemm   <<<dim3(6, 32, 4),  256, 0, stream>>>(x, wqkv, Qb, Kb, Vb);
    flash_attn <<<dim3(16, 16, 2), 256, 0, stream>>>(Qb, Kb, Vb, Opart, ml);
    proj_gemm  <<<dim3(2, 32, 4),  256, 0, stream>>>(Opart, ml, wproj, projbf, psum);
    bn_finalize<<<256,             256, 0, stream>>>(psum, stats);
    bn_apply   <<<4096,            256, 0, stream>>>(projbf, stats, gamma, beta, x, out);
}

// Round 16
// 118.470 us; speedup vs baseline: 1.1335x; 1.1218x over previous
//
#include <hip/hip_runtime.h>
#include <stdint.h>

typedef float          f32x4  __attribute__((ext_vector_type(4)));
typedef __bf16         bf16x8 __attribute__((ext_vector_type(8)));
typedef unsigned short u16x4  __attribute__((ext_vector_type(4)));
typedef unsigned short u16x8  __attribute__((ext_vector_type(8)));

__device__ __forceinline__ float bf2f(unsigned short u) {
    union { uint32_t i; float f; } v; v.i = ((uint32_t)u) << 16; return v.f;
}
__device__ __forceinline__ unsigned short bfc(float f) {
    return __builtin_bit_cast(unsigned short, (__bf16)f);
}
__device__ __forceinline__ f32x4 mfma16(bf16x8 a, bf16x8 b, f32x4 c) {
    return __builtin_amdgcn_mfma_f32_16x16x32_bf16(a, b, c, 0, 0, 0);
}
// async global->LDS, 16B per lane; LDS dest = wave-uniform base + lane*16
__device__ __forceinline__ void async16(const unsigned short* g, unsigned short* l) {
    __builtin_amdgcn_global_load_lds(
        (const __attribute__((address_space(1))) void*)g,
        (__attribute__((address_space(3))) void*)l, 16, 0, 0);
}

#define QSC 0.18033688f   /* 0.125 * log2(e): S produced in exp2 domain */

// ---------------------------------------------------------------------------
// Kernel 1: QKV GEMM.  C[o][n] = sum_c Wqkv[o][c] * X[b][c][n],  o in [0,768)
// f32 inputs -> bf16 LDS staging.  Q written pre-scaled by 0.125*log2e.
// Xt tile uses a both-sides column XOR swizzle (col ^= ((n>>3)&7)<<3):
// the transpose scatter was a 16-way bank conflict (lane stride 576 ushorts
// = 0 mod 64); the XOR spreads the 16 colliding lanes across 8 granules
// (2-way = free).  Reads apply the same XOR; b128 alignment preserved.
// XCD-chunked swizzle (768 = 8 x 96).
// ---------------------------------------------------------------------------
__global__ __launch_bounds__(256) void qkv_gemm(
    const float* __restrict__ x, const float* __restrict__ wqkv,
    unsigned short* __restrict__ Qb, unsigned short* __restrict__ Kb,
    unsigned short* __restrict__ Vb) {
    const int flat = (blockIdx.z * 32 + blockIdx.y) * 6 + blockIdx.x;  // 0..767
    const int v = (flat & 7) * 96 + (flat >> 3);    // bijective (768 = 8*96)
    const int mt = v % 6;
    const int rest = v / 6;
    const int nt = rest & 31;
    const int b  = rest >> 5;
    const int o0 = mt * 128, n0 = nt * 128;
    __shared__ __align__(16) unsigned short Wt[128 * 72];   // [o][c] pad 72
    __shared__ __align__(16) unsigned short Xt[128 * 72];   // [n][c] pad 72, col-XOR
    const int t = threadIdx.x;
    const int lane = t & 63, w = t >> 6;
    const int wr = w >> 1, wc = w & 1;
    const int l15 = lane & 15, g = lane >> 4;

    f32x4 acc[4][4];
    const f32x4 zero = {0.f, 0.f, 0.f, 0.f};
    for (int i = 0; i < 4; i++) for (int j = 0; j < 4; j++) acc[i][j] = zero;

    for (int k0 = 0; k0 < 256; k0 += 64) {
        {
            const int row = t >> 3, col = (t & 7) * 8;
            #pragma unroll
            for (int r = 0; r < 4; r++) {
                const float* p = wqkv + (size_t)(o0 + row + r * 32) * 256 + k0 + col;
                f32x4 v0 = *(const f32x4*)p;
                f32x4 v1 = *(const f32x4*)(p + 4);
                u16x8 o8 = { bfc(v0[0]), bfc(v0[1]), bfc(v0[2]), bfc(v0[3]),
                             bfc(v1[0]), bfc(v1[1]), bfc(v1[2]), bfc(v1[3]) };
                *(u16x8*)(&Wt[(row + r * 32) * 72 + col]) = o8;
            }
        }
        {
            const int cl = t >> 4, nl = (t & 15) * 8;
            const int xw = (t & 7) << 3;      // == ((nl+j)>>3 & 7)<<3 for j<8
            #pragma unroll
            for (int r = 0; r < 4; r++) {
                const int c = k0 + cl + r * 16;
                const int colw = (cl + r * 16) ^ xw;
                const float* p = x + (size_t)(b * 512 + c) * 4096 + n0 + nl;
                f32x4 v0 = *(const f32x4*)p;
                f32x4 v1 = *(const f32x4*)(p + 4);
                #pragma unroll
                for (int j = 0; j < 4; j++) Xt[(nl + j) * 72 + colw] = bfc(v0[j]);
                #pragma unroll
                for (int j = 0; j < 4; j++) Xt[(nl + 4 + j) * 72 + colw] = bfc(v1[j]);
            }
        }
        __syncthreads();
        #pragma unroll
        for (int kk = 0; kk < 2; kk++) {
            bf16x8 af[4], bfr[4];
            #pragma unroll
            for (int i = 0; i < 4; i++)
                af[i] = *(const bf16x8*)(&Wt[(wr * 64 + i * 16 + l15) * 72 + kk * 32 + g * 8]);
            #pragma unroll
            for (int j = 0; j < 4; j++) {
                const int rrow = wc * 64 + j * 16 + l15;
                const int xr = (((rrow >> 3) & 7) << 3);
                bfr[j] = *(const bf16x8*)(&Xt[rrow * 72 + ((kk * 32 + g * 8) ^ xr)]);
            }
            #pragma unroll
            for (int i = 0; i < 4; i++)
                #pragma unroll
                for (int j = 0; j < 4; j++)
                    acc[i][j] = mfma16(af[i], bfr[j], acc[i][j]);
        }
        __syncthreads();
    }

    #pragma unroll
    for (int i = 0; i < 4; i++) {
        const int o = o0 + wr * 64 + i * 16 + g * 4;
        #pragma unroll
        for (int j = 0; j < 4; j++) {
            const int n = n0 + wc * 64 + j * 16 + l15;
            f32x4 a = acc[i][j];
            if (o < 256) {
                u16x4 pv = { bfc(a[0] * QSC), bfc(a[1] * QSC), bfc(a[2] * QSC), bfc(a[3] * QSC) };
                const int h = o >> 6, d = o & 63;
                *(u16x4*)(&Qb[(((size_t)(b * 4 + h)) * 4096 + n) * 64 + d]) = pv;
            } else if (o < 512) {
                u16x4 pv = { bfc(a[0]), bfc(a[1]), bfc(a[2]), bfc(a[3]) };
                const int oo = o - 256; const int h = oo >> 6, d = oo & 63;
                *(u16x4*)(&Kb[(((size_t)(b * 4 + h)) * 4096 + n) * 64 + d]) = pv;
            } else {
                const int oo = o - 512; const int h = oo >> 6, d = oo & 63;
                const size_t base = (((size_t)(b * 4 + h)) * 64 + d) * 4096 + n;
                Vb[base] = bfc(a[0]); Vb[base + 4096] = bfc(a[1]);
                Vb[base + 8192] = bfc(a[2]); Vb[base + 12288] = bfc(a[3]);
            }
        }
    }
}

// ---------------------------------------------------------------------------
// Kernel 2: flash attention, KV-split S=2 (2048-wide halves), MAX-FREE
// softmax, fat waves: 4 waves x 64 q-rows (QBLK=256), KVBLK=64, 32 iters.
// K and V fragments read from LDS ONCE per iteration, reused by 4 ntl
// sub-blocks.  K,V double-buffered [64][64] LDS (32 KB) via global_load_lds
// + XOR swizzle.  P in registers via k-space relabel sigma; l via ones-MFMA.
// Writes UNNORMALIZED O (bf16) + per-row l partials.  (Converged: ~75 us.)
// ---------------------------------------------------------------------------
__global__ __launch_bounds__(256, 2) void flash_attn(
    const unsigned short* __restrict__ Qb, const unsigned short* __restrict__ Kb,
    const unsigned short* __restrict__ Vb, unsigned short* __restrict__ Opart,
    float* __restrict__ ml) {
    __shared__ __align__(16) unsigned short Kt[2][64 * 64];   // 16 KB
    __shared__ __align__(16) unsigned short Vt[2][64 * 64];   // 16 KB

    // XCD-aware swizzle over 512 blocks (8 XCDs x 64)
    const int flat = (blockIdx.z * 16 + blockIdx.y) * 16 + blockIdx.x;
    const int nf = (flat & 7) * 64 + (flat >> 3);
    const int z  = nf >> 8;             // kv half: 0/1
    const int bh = (nf >> 4) & 15;      // 0..15
    const int nb = nf & 15;             // 0..15  (q-tile of 256)

    const int t = threadIdx.x, lane = t & 63, w = t >> 6;    // w = 0..3
    const int l15 = lane & 15, g = lane >> 4;
    const int xo = (l15 & 7) << 3;              // element-space XOR for K reads
    const int c0 = (g * 8) ^ xo, c1 = c0 ^ 32;
    // V b64 read column base (ushort units): block=(g>>1)^(l15&7), half=g&1
    const int vq = ((((g >> 1) ^ (l15 & 7)) << 3) | ((g & 1) << 2));

    // staging source addresses (pre-swizzled, within each 128B row)
    const int rb = lane >> 3;                                  // 0..7
    const int cbe = ((lane & 7) ^ rb) << 3;                    // element col offset
    const unsigned short* kgp = Kb + ((size_t)bh * 4096 + z * 2048 + w * 8 + rb) * 64 + cbe;
    const unsigned short* vgp = Vb + ((size_t)(bh * 64 + w * 8 + rb)) * 4096 + z * 2048 + cbe;

    auto stage = [&](int buf) {           // loads NEXT kv-tile, advances ptrs
        async16(kgp,          &Kt[buf][w * 512]);
        async16(kgp + 2048,   &Kt[buf][w * 512 + 2048]);
        async16(vgp,          &Vt[buf][w * 512]);
        async16(vgp + 131072, &Vt[buf][w * 512 + 2048]);
        kgp += 4096; vgp += 64;
    };

    // Q fragments (scaled into exp2 domain at QKV epilogue), 64 rows/wave
    bf16x8 qf[4][2];
    #pragma unroll
    for (int ntl = 0; ntl < 4; ++ntl) {
        const int nq = nb * 256 + w * 64 + ntl * 16 + l15;
        const unsigned short* qp = Qb + ((size_t)bh * 4096 + nq) * 64;
        qf[ntl][0] = *(const bf16x8*)(qp + g * 8);
        qf[ntl][1] = *(const bf16x8*)(qp + 32 + g * 8);
    }

    // ones A-fragment for the l-accumulating MFMA (bf16 1.0 = 0x3F80)
    const bf16x8 ones8 = __builtin_bit_cast(bf16x8,
        (u16x8){0x3F80, 0x3F80, 0x3F80, 0x3F80, 0x3F80, 0x3F80, 0x3F80, 0x3F80});

    f32x4 of[4][4];
    f32x4 lf[4];
    const f32x4 zero = {0.f, 0.f, 0.f, 0.f};
    #pragma unroll
    for (int dt = 0; dt < 4; ++dt)
        #pragma unroll
        for (int ntl = 0; ntl < 4; ++ntl) of[dt][ntl] = zero;
    lf[0] = zero; lf[1] = zero; lf[2] = zero; lf[3] = zero;

    stage(0);
    __syncthreads();

    for (int itp = 0; itp < 16; ++itp) {
        #pragma unroll
        for (int cur = 0; cur < 2; ++cur) {          // cur is compile-time
            if (itp * 2 + cur < 31) stage(cur ^ 1);

            // read K and V fragments ONCE (reused by all 4 ntl)
            bf16x8 ka[4][2], va[4][2];
            #pragma unroll
            for (int mt = 0; mt < 4; ++mt) {
                const int kro = (mt * 16 + l15) * 64;
                ka[mt][0] = *(const bf16x8*)(&Kt[cur][kro + c0]);
                ka[mt][1] = *(const bf16x8*)(&Kt[cur][kro + c1]);
            }
            #pragma unroll
            for (int dt = 0; dt < 4; ++dt) {
                const unsigned short* vr = &Vt[cur][l15 * 64 + dt * 1024];
                u16x4 w00 = *(const u16x4*)(vr + (vq ^ 0));
                u16x4 w01 = *(const u16x4*)(vr + (vq ^ 16));
                u16x4 w10 = *(const u16x4*)(vr + (vq ^ 32));
                u16x4 w11 = *(const u16x4*)(vr + (vq ^ 48));
                va[dt][0] = __builtin_bit_cast(bf16x8,
                    __builtin_shufflevector(w00, w01, 0, 1, 2, 3, 4, 5, 6, 7));
                va[dt][1] = __builtin_bit_cast(bf16x8,
                    __builtin_shufflevector(w10, w11, 0, 1, 2, 3, 4, 5, 6, 7));
            }

            #pragma unroll
            for (int ntl = 0; ntl < 4; ++ntl) {
                // S^T (exp2 domain) for this 16-row slice
                f32x4 st[4];
                __builtin_amdgcn_s_setprio(1);
                #pragma unroll
                for (int mt = 0; mt < 4; ++mt)
                    st[mt] = mfma16(ka[mt][1], qf[ntl][1],
                                    mfma16(ka[mt][0], qf[ntl][0], zero));
                __builtin_amdgcn_s_setprio(0);

                // max-free softmax: P = exp2(S), packed into fragments
                u16x4 q0 = { bfc(__builtin_amdgcn_exp2f(st[0][0])),
                             bfc(__builtin_amdgcn_exp2f(st[0][1])),
                             bfc(__builtin_amdgcn_exp2f(st[0][2])),
                             bfc(__builtin_amdgcn_exp2f(st[0][3])) };
                u16x4 q1 = { bfc(__builtin_amdgcn_exp2f(st[1][0])),
                             bfc(__builtin_amdgcn_exp2f(st[1][1])),
                             bfc(__builtin_amdgcn_exp2f(st[1][2])),
                             bfc(__builtin_amdgcn_exp2f(st[1][3])) };
                u16x4 q2 = { bfc(__builtin_amdgcn_exp2f(st[2][0])),
                             bfc(__builtin_amdgcn_exp2f(st[2][1])),
                             bfc(__builtin_amdgcn_exp2f(st[2][2])),
                             bfc(__builtin_amdgcn_exp2f(st[2][3])) };
                u16x4 q3 = { bfc(__builtin_amdgcn_exp2f(st[3][0])),
                             bfc(__builtin_amdgcn_exp2f(st[3][1])),
                             bfc(__builtin_amdgcn_exp2f(st[3][2])),
                             bfc(__builtin_amdgcn_exp2f(st[3][3])) };
                bf16x8 pb0 = __builtin_bit_cast(bf16x8,
                    __builtin_shufflevector(q0, q1, 0, 1, 2, 3, 4, 5, 6, 7));
                bf16x8 pb1 = __builtin_bit_cast(bf16x8,
                    __builtin_shufflevector(q2, q3, 0, 1, 2, 3, 4, 5, 6, 7));

                // l + PV on the matrix pipe (operands all in registers)
                __builtin_amdgcn_s_setprio(1);
                lf[ntl] = mfma16(ones8, pb1, mfma16(ones8, pb0, lf[ntl]));
                #pragma unroll
                for (int dt = 0; dt < 4; ++dt)
                    of[dt][ntl] = mfma16(va[dt][1], pb1,
                                         mfma16(va[dt][0], pb0, of[dt][ntl]));
                __builtin_amdgcn_s_setprio(0);
            }
            __syncthreads();        // drains prefetch + guards buffer swap
        }
    }

    // epilogue: unnormalized O (bf16) + per-row l partials (lane-local)
    #pragma unroll
    for (int ntl = 0; ntl < 4; ++ntl) {
        const int nq = nb * 256 + w * 64 + ntl * 16 + l15;
        const size_t obase = ((size_t)((z * 16 + bh) * 4096 + nq)) * 64;
        #pragma unroll
        for (int dt = 0; dt < 4; ++dt) {
            u16x4 pv = { bfc(of[dt][ntl][0]), bfc(of[dt][ntl][1]),
                         bfc(of[dt][ntl][2]), bfc(of[dt][ntl][3]) };
            *(u16x4*)(&Opart[obase + dt * 16 + g * 4]) = pv;
        }
        if (g == 0) ml[z * 65536 + bh * 4096 + nq] = lf[ntl][0];
    }
}

// ---------------------------------------------------------------------------
// Kernel 3: proj GEMM with FUSED attention merge in the B staging:
// att = (O1+O2)/(l1+l2), BK=64 == head_dim.
// XCD-chunked swizzle (256 = 8 x 32).
// ---------------------------------------------------------------------------
__global__ __launch_bounds__(256) void proj_gemm(
    const unsigned short* __restrict__ Opart, const float* __restrict__ ml,
    const float* __restrict__ wproj,
    unsigned short* __restrict__ projbf, float* __restrict__ psum) {
    const int flat = (blockIdx.z * 32 + blockIdx.y) * 2 + blockIdx.x;  // 0..255
    const int v = (flat & 7) * 32 + (flat >> 3);    // bijective (256 = 8*32)
    const int mt = v & 1;
    const int rest = v >> 1;
    const int nt = rest & 31;
    const int b  = rest >> 5;
    const int o0 = mt * 128, n0 = nt * 128;
    __shared__ __align__(16) unsigned short Wt[128 * 72];
    __shared__ __align__(16) unsigned short Bt[128 * 72];
    const int t = threadIdx.x;
    const int lane = t & 63, w = t >> 6;
    const int wr = w >> 1, wc = w & 1;
    const int l15 = lane & 15, g = lane >> 4;

    f32x4 acc[4][4];
    const f32x4 zero = {0.f, 0.f, 0.f, 0.f};
    for (int i = 0; i < 4; i++) for (int j = 0; j < 4; j++) acc[i][j] = zero;

    for (int k0 = 0; k0 < 256; k0 += 64) {
        const int row = t >> 3, col = (t & 7) * 8;
        const int h = k0 >> 6;
        #pragma unroll
        for (int r = 0; r < 4; r++) {
            const float* p = wproj + (size_t)(o0 + row + r * 32) * 256 + k0 + col;
            f32x4 v0 = *(const f32x4*)p;
            f32x4 v1 = *(const f32x4*)(p + 4);
            u16x8 o8 = { bfc(v0[0]), bfc(v0[1]), bfc(v0[2]), bfc(v0[3]),
                         bfc(v1[0]), bfc(v1[1]), bfc(v1[2]), bfc(v1[3]) };
            *(u16x8*)(&Wt[(row + r * 32) * 72 + col]) = o8;
            // fused merge: att[b][n][h*64+col..] = (O1+O2)/(l1+l2)
            const int n = n0 + row + r * 32;
            const int qidx = (b * 4 + h) * 4096 + n;
            const float inv = 1.f / (ml[qidx] + ml[65536 + qidx]);
            u16x8 m1 = *(const u16x8*)(Opart + (size_t)qidx * 64 + col);
            u16x8 m2 = *(const u16x8*)(Opart + 4194304u + (size_t)qidx * 64 + col);
            u16x8 a;
            #pragma unroll
            for (int j = 0; j < 8; ++j) a[j] = bfc((bf2f(m1[j]) + bf2f(m2[j])) * inv);
            *(u16x8*)(&Bt[(row + r * 32) * 72 + col]) = a;
        }
        __syncthreads();
        #pragma unroll
        for (int kk = 0; kk < 2; kk++) {
            bf16x8 af[4], bfr[4];
            #pragma unroll
            for (int i = 0; i < 4; i++)
                af[i] = *(const bf16x8*)(&Wt[(wr * 64 + i * 16 + l15) * 72 + kk * 32 + g * 8]);
            #pragma unroll
            for (int j = 0; j < 4; j++)
                bfr[j] = *(const bf16x8*)(&Bt[(wc * 64 + j * 16 + l15) * 72 + kk * 32 + g * 8]);
            #pragma unroll
            for (int i = 0; i < 4; i++)
                #pragma unroll
                for (int j = 0; j < 4; j++)
                    acc[i][j] = mfma16(af[i], bfr[j], acc[i][j]);
        }
        __syncthreads();
    }

    #pragma unroll
    for (int i = 0; i < 4; i++) {
        const int o = o0 + wr * 64 + i * 16 + g * 4;
        #pragma unroll
        for (int j = 0; j < 4; j++) {
            const int n = n0 + wc * 64 + j * 16 + l15;
            f32x4 a = acc[i][j];
            #pragma unroll
            for (int r = 0; r < 4; r++)
                projbf[((size_t)(b * 256 + o + r)) * 4096 + n] = bfc(a[r]);
        }
        // BN partials over this wave's 64 n-columns (f32, pre-rounding)
        f32x4 s = acc[i][0], q;
        #pragma unroll
        for (int r = 0; r < 4; ++r) q[r] = acc[i][0][r] * acc[i][0][r];
        #pragma unroll
        for (int j = 1; j < 4; ++j)
            #pragma unroll
            for (int r = 0; r < 4; ++r) {
                s[r] += acc[i][j][r];
                q[r] = fmaf(acc[i][j][r], acc[i][j][r], q[r]);
            }
        #pragma unroll
        for (int m = 1; m < 16; m <<= 1) {
            #pragma unroll
            for (int r = 0; r < 4; ++r) {
                s[r] += __shfl_xor(s[r], m, 64);
                q[r] += __shfl_xor(q[r], m, 64);
            }
        }
        if (l15 == 0) {
            const int slot = (b * 32 + nt) * 2 + wc;
            *(f32x4*)(&psum[slot * 256 + o]) = s;
            *(f32x4*)(&psum[65536 + slot * 256 + o]) = q;
        }
    }
}

// ---------------------------------------------------------------------------
// Kernel 4: BN finalize.  One block per channel o; 256 threads over slots.
// ---------------------------------------------------------------------------
__global__ __launch_bounds__(256) void bn_finalize(const float* __restrict__ psum,
                                                   float* __restrict__ stats) {
    const int o = blockIdx.x, t = threadIdx.x;
    const int lane = t & 63, w = t >> 6;
    float s = psum[t * 256 + o];
    float q = psum[65536 + t * 256 + o];
    #pragma unroll
    for (int m = 1; m < 64; m <<= 1) {
        s += __shfl_xor(s, m, 64);
        q += __shfl_xor(q, m, 64);
    }
    __shared__ float red[8];
    if (lane == 0) { red[w] = s; red[4 + w] = q; }
    __syncthreads();
    if (t == 0) {
        const float S = red[0] + red[1] + red[2] + red[3];
        const float Q = red[4] + red[5] + red[6] + red[7];
        const float mean = S * (1.f / 16384.f);
        const float var = Q * (1.f / 16384.f) - mean * mean;
        stats[o] = mean;
        stats[256 + o] = rsqrtf(var + 1e-5f);
    }
}

// ---------------------------------------------------------------------------
// Kernel 5: BN apply + gamma/beta + concat skip.  proj bf16 in, f32 out.
// ---------------------------------------------------------------------------
__global__ __launch_bounds__(256) void bn_apply(
    const unsigned short* __restrict__ projbf, const float* __restrict__ stats,
    const float* __restrict__ gamma, const float* __restrict__ beta,
    const float* __restrict__ x, float* __restrict__ out) {
    const size_t idx8 = ((size_t)blockIdx.x * 256 + threadIdx.x) * 8;
    const int n  = (int)(idx8 & 4095);
    const int ch = (int)((idx8 >> 12) & 511);
    const int b  = (int)(idx8 >> 21);
    if (ch < 256) {
        const float mean = stats[ch], rstd = stats[256 + ch];
        const float sc = gamma[ch] * rstd;
        const float sh = beta[ch] - mean * sc;
        u16x8 pv = *(const u16x8*)(projbf + (((size_t)(b * 256 + ch)) << 12) + n);
        f32x4 o0, o1;
        #pragma unroll
        for (int j = 0; j < 4; j++) { o0[j] = bf2f(pv[j]) * sc + sh; o1[j] = bf2f(pv[4 + j]) * sc + sh; }
        *(f32x4*)(out + idx8) = o0;
        *(f32x4*)(out + idx8 + 4) = o1;
    } else {
        *(f32x4*)(out + idx8)     = *(const f32x4*)(x + idx8);
        *(f32x4*)(out + idx8 + 4) = *(const f32x4*)(x + idx8 + 4);
    }
}

// ---------------------------------------------------------------------------
// Workspace overlay (offsets in bytes):
//   phase A (qkv+flash):  Qb 0..8M, Kb 8..16M, Vb 16..24M,
//                         Opart 24..40M (both halves), ml 41..41.5M (f32)
//   phase B (proj+bn):    projbf 0..8M (over dead Qb),
//                         psum 9..9.5M (over dead Kb), stats 9.75M
// ---------------------------------------------------------------------------
extern "C" void kernel_launch(void* const* d_in, const int* in_sizes, int n_in,
                              void* d_out, int out_size, void* d_ws, size_t ws_size,
                              hipStream_t stream) {
    const float* x     = (const float*)d_in[0];
    const float* wqkv  = (const float*)d_in[1];
    const float* wproj = (const float*)d_in[2];
    const float* gamma = (const float*)d_in[3];
    const float* beta  = (const float*)d_in[4];
    float* out = (float*)d_out;

    char* ws = (char*)d_ws;
    unsigned short* Qb     = (unsigned short*)(ws);
    unsigned short* Kb     = (unsigned short*)(ws + (8ull  << 20));
    unsigned short* Vb     = (unsigned short*)(ws + (16ull << 20));
    unsigned short* Opart  = (unsigned short*)(ws + (24ull << 20));
    float*          ml     = (float*)(ws + (41ull << 20));
    unsigned short* projbf = (unsigned short*)(ws);                  // over Qb
    float*          psum   = (float*)(ws + (9ull << 20));            // over Kb
    float*          stats  = (float*)(ws + (9ull << 20) + (768u << 10));

    qkv_gemm   <<<dim3(6, 32, 4),  256, 0, stream>>>(x, wqkv, Qb, Kb, Vb);
    flash_attn <<<dim3(16, 16, 2), 256, 0, stream>>>(Qb, Kb, Vb, Opart, ml);
    proj_gemm  <<<dim3(2, 32, 4),  256, 0, stream>>>(Opart, ml, wproj, projbf, psum);
    bn_finalize<<<256,             256, 0, stream>>>(psum, stats);
    bn_apply   <<<4096,            256, 0, stream>>>(projbf, stats, gamma, beta, x, out);
}